// Round 1
// baseline (370.213 us; speedup 1.0000x reference)
//
#include <hip/hip_runtime.h>

#define NB 16     // batches
#define NV 19     // vertices
#define NE 361    // edges per graph
#define NL 256    // seq len
#define ND 64     // d_model

// One block per (b, l). 256 threads = 4 waves.
__global__ __launch_bounds__(256, 3) void edge_learner_kernel(
    const float* __restrict__ hs,      // (B*V, L, D)
    const float* __restrict__ ew_in,   // (B*E, L)
    const float* __restrict__ W1,      // (129, 64)
    const float* __restrict__ b1,      // (64,)
    const float* __restrict__ W2,      // (64, 32)
    const float* __restrict__ b2,      // (32,)
    const float* __restrict__ W3,      // (32, 1)
    const float* __restrict__ b3,      // (1,)
    const float* __restrict__ skip_p,  // (1,)
    const int*   __restrict__ eidx,    // (2, B*E, L)
    float* __restrict__ out)           // (B*E, L)
{
    __shared__ __align__(16) float W1s[128 * 64];   // rows 0..127 of W1
    __shared__ __align__(16) float hs_s[NV * 64];   // node features at (b, :, l, :)
    __shared__ __align__(16) float A[NV * 128];     // precomputed node projections
    __shared__ int   src_s[NE];
    __shared__ int   tgt_s[NE];
    __shared__ float ew_s[NE];
    __shared__ __align__(16) float h1_s[4 * 64];    // per-wave h1 buffer

    const int tid  = threadIdx.x;
    const int lane = tid & 63;
    const int wave = tid >> 6;
    const int bid  = blockIdx.x;
    const int b    = bid >> 8;    // bid / NL  (NL == 256)
    const int l    = bid & 255;   // bid % NL

    // ---- per-lane register constants ----
    const int j = lane & 31;      // layer-2 output channel
    const int h = lane >> 5;      // layer-2 K-half
    float w2r[32];
    #pragma unroll
    for (int k = 0; k < 32; ++k) w2r[k] = W2[(32 * h + k) * 32 + j];
    const float b1r  = b1[lane];
    const float w1lr = W1[128 * 64 + lane];   // W1 row 128 (edge-weight row)
    const float b2r  = b2[j];
    const float w3r  = W3[j];
    const float b3v  = b3[0];
    const float skip = skip_p[0];

    // ---- stage W1 rows 0..127 ----
    for (int i = tid; i < 128 * 64; i += 256) W1s[i] = W1[i];

    // ---- stage hs slice: hs[(b*V+v), l, k] ----
    for (int i = tid; i < NV * 64; i += 256) {
        int v = i >> 6, k = i & 63;
        hs_s[i] = hs[((size_t)(b * NV + v) * NL + l) * ND + k];
    }

    // ---- stage edge metadata for this (b, l) ----
    for (int e = tid; e < NE; e += 256) {
        size_t row = (size_t)(b * NE + e) * NL + l;
        src_s[e] = eidx[row] % NV;
        tgt_s[e] = eidx[(size_t)NB * NE * NL + row] % NV;
        ew_s[e]  = ew_in[row];
    }
    __syncthreads();

    // ---- precompute A[v][c]: c<64 -> src proj, c>=64 -> tgt proj ----
    // A[v][half*64+oc] = sum_k hs_s[v][k] * W1s[half*64+k][oc]
    for (int q = tid; q < NV * 32; q += 256) {   // quad outputs (608 total)
        int o    = q * 4;
        int v    = o >> 7;
        int c    = o & 127;
        int half = c >> 6;
        int oc0  = c & 63;           // multiple of 4
        const float* wbase = &W1s[half * 64 * 64 + oc0];
        const float* hrow  = &hs_s[v * 64];
        float a0 = 0.f, a1 = 0.f, a2 = 0.f, a3 = 0.f;
        #pragma unroll 8
        for (int k = 0; k < 64; ++k) {
            float  hv = hrow[k];
            float4 w  = *(const float4*)&wbase[k * 64];
            a0 += hv * w.x; a1 += hv * w.y; a2 += hv * w.z; a3 += hv * w.w;
        }
        float4 r; r.x = a0; r.y = a1; r.z = a2; r.w = a3;
        *(float4*)&A[v * 128 + c] = r;
    }
    __syncthreads();

    // ---- edge loop: one wave per edge (no block-wide sync below) ----
    for (int e = wave; e < NE; e += 4) {
        const int   src = src_s[e];
        const int   tgt = tgt_s[e];
        const float ew  = ew_s[e];

        // layer 1: lane = output channel
        float t1 = A[src * 128 + lane] + A[tgt * 128 + 64 + lane]
                 + ew * w1lr + b1r;
        float h1 = t1 / (1.f + __expf(-t1));      // silu
        h1_s[wave * 64 + lane] = h1;
        asm volatile("s_waitcnt lgkmcnt(0)" ::: "memory");  // wave-internal LDS RAW

        // layer 2: lane (j, h) computes partial over K-half h
        const float* h1p = &h1_s[wave * 64 + 32 * h];
        float acc = 0.f;
        #pragma unroll
        for (int k = 0; k < 32; ++k) acc += h1p[k] * w2r[k];
        acc += __shfl_xor(acc, 32);               // combine K-halves
        float t2 = acc + b2r;
        float h2 = t2 / (1.f + __expf(-t2));      // silu

        // layer 3: dot over 32 channels (butterfly within each 32-lane half)
        float p = h2 * w3r;
        p += __shfl_xor(p, 16);
        p += __shfl_xor(p, 8);
        p += __shfl_xor(p, 4);
        p += __shfl_xor(p, 2);
        p += __shfl_xor(p, 1);
        float wgt = 1.f / (1.f + __expf(-(p + b3v)));  // sigmoid
        float res = skip * ew + (1.f - skip) * wgt;

        if (lane == 0) out[(size_t)(b * NE + e) * NL + l] = res;
    }
}

extern "C" void kernel_launch(void* const* d_in, const int* in_sizes, int n_in,
                              void* d_out, int out_size, void* d_ws, size_t ws_size,
                              hipStream_t stream) {
    const float* hs   = (const float*)d_in[0];
    const float* ew   = (const float*)d_in[1];
    const float* W1   = (const float*)d_in[2];
    const float* b1   = (const float*)d_in[3];
    const float* W2   = (const float*)d_in[4];
    const float* b2   = (const float*)d_in[5];
    const float* W3   = (const float*)d_in[6];
    const float* b3   = (const float*)d_in[7];
    const float* skip = (const float*)d_in[8];
    const int*   eidx = (const int*)d_in[9];
    float* outp = (float*)d_out;

    dim3 grid(NB * NL);   // 4096 blocks, one per (b, l)
    dim3 block(256);
    hipLaunchKernelGGL(edge_learner_kernel, grid, block, 0, stream,
                       hs, ew, W1, b1, W2, b2, W3, b3, skip, eidx, outp);
}

// Round 2
// 101.913 us; speedup vs baseline: 3.6326x; 3.6326x over previous
//
#include <hip/hip_runtime.h>

#define NB 16     // batches
#define NV 19     // vertices
#define NE 361    // edges per graph
#define NL 256    // seq len
#define ND 64     // d_model
#define NT 23     // edge tiles of 16 (ceil(361/16))
#define NEP (NT * 16)   // 368 padded edges
#define ASTRIDE 136     // bf16 elems per A row: 272B, 16B-aligned, banks spread by v*4

typedef __attribute__((ext_vector_type(8))) short bf16x8;
typedef __attribute__((ext_vector_type(4))) float f32x4;

__device__ __forceinline__ short f2bf(float f) {   // RNE round to bf16
    unsigned u = __builtin_bit_cast(unsigned, f);
    unsigned r = (u + 0x7FFFu + ((u >> 16) & 1u)) >> 16;
    return (short)r;
}
__device__ __forceinline__ float bf2f(short s) {
    unsigned u = ((unsigned)(unsigned short)s) << 16;
    return __builtin_bit_cast(float, u);
}
__device__ __forceinline__ float silu(float x) { return x / (1.f + __expf(-x)); }

// One block per (b, l). 256 threads = 4 waves.
__global__ __launch_bounds__(256, 3) void edge_learner_kernel(
    const float* __restrict__ hs,      // (B*V, L, D)
    const float* __restrict__ ew_in,   // (B*E, L)
    const float* __restrict__ W1,      // (129, 64)
    const float* __restrict__ b1,      // (64,)
    const float* __restrict__ W2,      // (64, 32)
    const float* __restrict__ b2,      // (32,)
    const float* __restrict__ W3,      // (32, 1)
    const float* __restrict__ b3,      // (1,)
    const float* __restrict__ skip_p,  // (1,)
    const int*   __restrict__ eidx,    // (2, B*E, L)
    float* __restrict__ out)           // (B*E, L)
{
    __shared__ __align__(16) short A_s[NV * ASTRIDE];  // node projections, bf16
    __shared__ int   srco_s[NEP];   // src*ASTRIDE  (A elem offset)
    __shared__ int   tgto_s[NEP];   // tgt*ASTRIDE + 64
    __shared__ float ew_s[NEP];

    const int tid  = threadIdx.x;
    const int lane = tid & 63;
    const int wave = tid >> 6;
    const int lq   = lane >> 4;    // quarter (k-group)
    const int lm   = lane & 15;    // row/col within fragment
    const int bid  = blockIdx.x;
    const int b    = bid >> 8;     // bid / NL
    const int l    = bid & 255;    // bid % NL

    // ---------- stage edge metadata ----------
    for (int e = tid; e < NEP; e += 256) {
        if (e < NE) {
            size_t row = (size_t)(b * NE + e) * NL + l;
            srco_s[e] = (eidx[row] % NV) * ASTRIDE;
            tgto_s[e] = (eidx[(size_t)NB * NE * NL + row] % NV) * ASTRIDE + 64;
            ew_s[e]   = ew_in[row];
        } else {
            srco_s[e] = 0; tgto_s[e] = 64; ew_s[e] = 0.f;
        }
    }

    // ---------- per-lane constants (registers) ----------
    // phase-3 channels for this lane: ch(ks,i) = ks*32 + lq*8 + i
    float w1l_r[16], b1_r[16];
    #pragma unroll
    for (int ks = 0; ks < 2; ++ks)
        #pragma unroll
        for (int i = 0; i < 8; ++i) {
            int ch = ks * 32 + lq * 8 + i;
            w1l_r[ks * 8 + i] = W1[128 * 64 + ch];
            b1_r[ks * 8 + i]  = b1[ch];
        }
    // W2 B-fragments: w2f[nt][ks], lane holds col nt*16+lm, k = ks*32+lq*8+i
    bf16x8 w2f[2][2];
    #pragma unroll
    for (int nt = 0; nt < 2; ++nt)
        #pragma unroll
        for (int ks = 0; ks < 2; ++ks)
            #pragma unroll
            for (int i = 0; i < 8; ++i)
                w2f[nt][ks][i] = f2bf(W2[(ks * 32 + lq * 8 + i) * 32 + nt * 16 + lm]);
    const float b2r0 = b2[lm],      b2r1 = b2[16 + lm];
    const float w3a  = W3[lm],      w3b  = W3[16 + lm];
    const float b3v  = b3[0];
    const float skip = skip_p[0];

    // ---------- phase 2: A[v][c] = node projections via MFMA ----------
    // wave w owns output cols c in [32w, 32w+32); weight half = w>>1, oc0 = 32*(w&1)
    {
        const int half = wave >> 1;
        const int oc0  = (wave & 1) * 32;
        bf16x8 w1f[2][2];   // [nt][ks]
        #pragma unroll
        for (int nt = 0; nt < 2; ++nt)
            #pragma unroll
            for (int ks = 0; ks < 2; ++ks)
                #pragma unroll
                for (int i = 0; i < 8; ++i)
                    w1f[nt][ks][i] = f2bf(
                        W1[(half * 64 + ks * 32 + lq * 8 + i) * 64 + oc0 + nt * 16 + lm]);

        f32x4 acc00 = {0,0,0,0}, acc01 = {0,0,0,0}, acc10 = {0,0,0,0}, acc11 = {0,0,0,0};
        #pragma unroll
        for (int Mt = 0; Mt < 2; ++Mt) {
            int v  = Mt * 16 + lm;
            int vc = v < NV ? v : NV - 1;            // clamp pad rows
            const float* hp = hs + ((size_t)(b * NV + vc) * NL + l) * ND;
            bf16x8 af[2];
            #pragma unroll
            for (int ks = 0; ks < 2; ++ks) {
                float4 x0 = *(const float4*)&hp[ks * 32 + lq * 8];
                float4 x1 = *(const float4*)&hp[ks * 32 + lq * 8 + 4];
                af[ks][0] = f2bf(x0.x); af[ks][1] = f2bf(x0.y);
                af[ks][2] = f2bf(x0.z); af[ks][3] = f2bf(x0.w);
                af[ks][4] = f2bf(x1.x); af[ks][5] = f2bf(x1.y);
                af[ks][6] = f2bf(x1.z); af[ks][7] = f2bf(x1.w);
            }
            if (Mt == 0) {
                acc00 = __builtin_amdgcn_mfma_f32_16x16x32_bf16(af[0], w1f[0][0], acc00, 0, 0, 0);
                acc00 = __builtin_amdgcn_mfma_f32_16x16x32_bf16(af[1], w1f[0][1], acc00, 0, 0, 0);
                acc01 = __builtin_amdgcn_mfma_f32_16x16x32_bf16(af[0], w1f[1][0], acc01, 0, 0, 0);
                acc01 = __builtin_amdgcn_mfma_f32_16x16x32_bf16(af[1], w1f[1][1], acc01, 0, 0, 0);
            } else {
                acc10 = __builtin_amdgcn_mfma_f32_16x16x32_bf16(af[0], w1f[0][0], acc10, 0, 0, 0);
                acc10 = __builtin_amdgcn_mfma_f32_16x16x32_bf16(af[1], w1f[0][1], acc10, 0, 0, 0);
                acc11 = __builtin_amdgcn_mfma_f32_16x16x32_bf16(af[0], w1f[1][0], acc11, 0, 0, 0);
                acc11 = __builtin_amdgcn_mfma_f32_16x16x32_bf16(af[1], w1f[1][1], acc11, 0, 0, 0);
            }
        }
        // write A: row v = Mt*16 + lq*4 + r, col c = wave*32 + nt*16 + lm
        #pragma unroll
        for (int r = 0; r < 4; ++r) {
            int v0 = lq * 4 + r;                     // Mt = 0 rows (always < 16 < NV)
            A_s[v0 * ASTRIDE + wave * 32 + lm]      = f2bf(acc00[r]);
            A_s[v0 * ASTRIDE + wave * 32 + 16 + lm] = f2bf(acc01[r]);
            int v1 = 16 + lq * 4 + r;                // Mt = 1 rows, guard v < 19
            if (v1 < NV) {
                A_s[v1 * ASTRIDE + wave * 32 + lm]      = f2bf(acc10[r]);
                A_s[v1 * ASTRIDE + wave * 32 + 16 + lm] = f2bf(acc11[r]);
            }
        }
    }
    __syncthreads();

    // ---------- phase 3: edge tiles of 16, one wave per tile ----------
    for (int t = wave; t < NT; t += 4) {
        const int ebase = t * 16;
        const int e  = ebase + lm;        // this lane's edge (layer-1 role)
        const int so = srco_s[e];
        const int to = tgto_s[e];
        const float ew = ew_s[e];

        // layer 1 -> bf16 A-fragments (lane row = lm = edge, k = ks*32+lq*8+i)
        bf16x8 a1[2];
        #pragma unroll
        for (int ks = 0; ks < 2; ++ks) {
            const bf16x8 as = *(const bf16x8*)&A_s[so + ks * 32 + lq * 8];
            const bf16x8 at = *(const bf16x8*)&A_s[to + ks * 32 + lq * 8];
            #pragma unroll
            for (int i = 0; i < 8; ++i) {
                float t1 = bf2f(as[i]) + bf2f(at[i])
                         + ew * w1l_r[ks * 8 + i] + b1_r[ks * 8 + i];
                a1[ks][i] = f2bf(silu(t1));
            }
        }

        // layer 2: (16 edges x 64) @ (64 x 32) via 4 MFMAs
        f32x4 c0 = {0,0,0,0}, c1 = {0,0,0,0};
        c0 = __builtin_amdgcn_mfma_f32_16x16x32_bf16(a1[0], w2f[0][0], c0, 0, 0, 0);
        c0 = __builtin_amdgcn_mfma_f32_16x16x32_bf16(a1[1], w2f[0][1], c0, 0, 0, 0);
        c1 = __builtin_amdgcn_mfma_f32_16x16x32_bf16(a1[0], w2f[1][0], c1, 0, 0, 0);
        c1 = __builtin_amdgcn_mfma_f32_16x16x32_bf16(a1[1], w2f[1][1], c1, 0, 0, 0);

        // epilogue: silu, layer 3 partial (cols j=lm and j=16+lm), rows = edges
        float p0, p1, p2, p3;
        {
            float h;
            h = silu(c0[0] + b2r0); p0 = h * w3a;  h = silu(c1[0] + b2r1); p0 += h * w3b;
            h = silu(c0[1] + b2r0); p1 = h * w3a;  h = silu(c1[1] + b2r1); p1 += h * w3b;
            h = silu(c0[2] + b2r0); p2 = h * w3a;  h = silu(c1[2] + b2r1); p2 += h * w3b;
            h = silu(c0[3] + b2r0); p3 = h * w3a;  h = silu(c1[3] + b2r1); p3 += h * w3b;
        }
        // reduce over the 16 cols (lanes sharing lq): butterfly within 16-lane groups
        #pragma unroll
        for (int s = 1; s < 16; s <<= 1) {
            p0 += __shfl_xor(p0, s);
            p1 += __shfl_xor(p1, s);
            p2 += __shfl_xor(p2, s);
            p3 += __shfl_xor(p3, s);
        }
        // lanes lm<4 store edges: row = lq*4 + (lane&3)
        if (lm < 4) {
            int er = ebase + lq * 4 + (lane & 3);
            if (er < NE) {
                float ps = (lane & 2) ? ((lane & 1) ? p3 : p2)
                                      : ((lane & 1) ? p1 : p0);
                float wgt = 1.f / (1.f + __expf(-(ps + b3v)));
                float ewr = ew_s[er];
                out[(size_t)(b * NE + er) * NL + l] = skip * ewr + (1.f - skip) * wgt;
            }
        }
    }
}

extern "C" void kernel_launch(void* const* d_in, const int* in_sizes, int n_in,
                              void* d_out, int out_size, void* d_ws, size_t ws_size,
                              hipStream_t stream) {
    const float* hs   = (const float*)d_in[0];
    const float* ew   = (const float*)d_in[1];
    const float* W1   = (const float*)d_in[2];
    const float* b1   = (const float*)d_in[3];
    const float* W2   = (const float*)d_in[4];
    const float* b2   = (const float*)d_in[5];
    const float* W3   = (const float*)d_in[6];
    const float* b3   = (const float*)d_in[7];
    const float* skip = (const float*)d_in[8];
    const int*   eidx = (const int*)d_in[9];
    float* outp = (float*)d_out;

    dim3 grid(NB * NL);   // 4096 blocks, one per (b, l)
    dim3 block(256);
    hipLaunchKernelGGL(edge_learner_kernel, grid, block, 0, stream,
                       hs, ew, W1, b1, W2, b2, W3, b3, skip, eidx, outp);
}

// Round 3
// 69.826 us; speedup vs baseline: 5.3019x; 1.4595x over previous
//
#include <hip/hip_runtime.h>

#define NB 16     // batches
#define NV 19     // vertices
#define NE 361    // edges per graph
#define NL 256    // seq len
#define ND 64     // d_model
#define NT 23     // edge tiles of 16 (ceil(361/16))
#define NEP (NT * 16)   // 368 padded edges
#define ASTRIDE 136     // bf16 elems per A row: 272B, 16B-aligned

typedef __attribute__((ext_vector_type(8))) short bf16x8;
typedef __attribute__((ext_vector_type(4))) float f32x4;
typedef __attribute__((ext_vector_type(2))) __bf16 bf16v2;

union bf8u { unsigned u[4]; bf16x8 v; uint4 q; };

__device__ __forceinline__ unsigned pack_bf16(float lo, float hi) {
    bf16v2 v; v.x = (__bf16)lo; v.y = (__bf16)hi;   // -> v_cvt_pk_bf16_f32
    return __builtin_bit_cast(unsigned, v);
}
__device__ __forceinline__ short f2bf(float f) {
    __bf16 h = (__bf16)f;
    return __builtin_bit_cast(short, h);
}
__device__ __forceinline__ float bflo(unsigned u) {
    return __builtin_bit_cast(float, u << 16);
}
__device__ __forceinline__ float bfhi(unsigned u) {
    return __builtin_bit_cast(float, u & 0xffff0000u);
}
__device__ __forceinline__ float silu(float x) {
    return x * __builtin_amdgcn_rcpf(1.f + __expf(-x));   // rcp+mul, no IEEE div
}
__device__ __forceinline__ float sigm(float x) {
    return __builtin_amdgcn_rcpf(1.f + __expf(-x));
}

// One block per (b, l). 256 threads = 4 waves.
__global__ __launch_bounds__(256, 4) void edge_learner_kernel(
    const float* __restrict__ hs,      // (B*V, L, D)
    const float* __restrict__ ew_in,   // (B*E, L)
    const float* __restrict__ W1,      // (129, 64)
    const float* __restrict__ b1,      // (64,)
    const float* __restrict__ W2,      // (64, 32)
    const float* __restrict__ b2,      // (32,)
    const float* __restrict__ W3,      // (32, 1)
    const float* __restrict__ b3,      // (1,)
    const float* __restrict__ skip_p,  // (1,)
    const int*   __restrict__ eidx,    // (2, B*E, L)
    float* __restrict__ out)           // (B*E, L)
{
    __shared__ __align__(16) short A_s[NV * ASTRIDE];  // node projections, bf16
    __shared__ int   srco_s[NEP];   // src*ASTRIDE
    __shared__ int   tgto_s[NEP];   // tgt*ASTRIDE + 64
    __shared__ float ew_s[NEP];

    const int tid  = threadIdx.x;
    const int lane = tid & 63;
    const int wave = tid >> 6;
    const int lq   = lane >> 4;    // quarter (k-group)
    const int lm   = lane & 15;    // row/col within fragment
    const int bid  = blockIdx.x;
    const int b    = bid >> 8;     // bid / NL
    const int l    = bid & 255;    // bid % NL

    // ---------- stage edge metadata ----------
    for (int e = tid; e < NEP; e += 256) {
        if (e < NE) {
            size_t row = (size_t)(b * NE + e) * NL + l;
            srco_s[e] = (eidx[row] % NV) * ASTRIDE;
            tgto_s[e] = (eidx[(size_t)NB * NE * NL + row] % NV) * ASTRIDE + 64;
            ew_s[e]   = ew_in[row];
        } else {
            srco_s[e] = 0; tgto_s[e] = 64; ew_s[e] = 0.f;
        }
    }

    // ---------- per-lane constants (registers) ----------
    float w1l_r[16], b1_r[16];     // phase-3 channels ch(ks,i) = ks*32 + lq*8 + i
    #pragma unroll
    for (int ks = 0; ks < 2; ++ks)
        #pragma unroll
        for (int i = 0; i < 8; ++i) {
            int ch = ks * 32 + lq * 8 + i;
            w1l_r[ks * 8 + i] = W1[128 * 64 + ch];
            b1_r[ks * 8 + i]  = b1[ch];
        }
    bf16x8 w2f[2][2];              // lane holds col nt*16+lm, k = ks*32+lq*8+i
    #pragma unroll
    for (int nt = 0; nt < 2; ++nt)
        #pragma unroll
        for (int ks = 0; ks < 2; ++ks)
            #pragma unroll
            for (int i = 0; i < 8; ++i)
                w2f[nt][ks][i] = f2bf(W2[(ks * 32 + lq * 8 + i) * 32 + nt * 16 + lm]);
    const float b2r0 = b2[lm],      b2r1 = b2[16 + lm];
    const float w3a  = W3[lm],      w3b  = W3[16 + lm];
    const float b3v  = b3[0];
    const float skip = skip_p[0];

    // ---------- phase 2: A[v][c] via MFMA; wave w owns cols [32w, 32w+32) ----------
    {
        const int half = wave >> 1;
        const int oc0  = (wave & 1) * 32;
        bf16x8 w1f[2][2];   // [nt][ks]
        #pragma unroll
        for (int nt = 0; nt < 2; ++nt)
            #pragma unroll
            for (int ks = 0; ks < 2; ++ks)
                #pragma unroll
                for (int i = 0; i < 8; ++i)
                    w1f[nt][ks][i] = f2bf(
                        W1[(half * 64 + ks * 32 + lq * 8 + i) * 64 + oc0 + nt * 16 + lm]);

        f32x4 acc00 = {0,0,0,0}, acc01 = {0,0,0,0}, acc10 = {0,0,0,0}, acc11 = {0,0,0,0};
        #pragma unroll
        for (int Mt = 0; Mt < 2; ++Mt) {
            int v  = Mt * 16 + lm;
            int vc = v < NV ? v : NV - 1;            // clamp pad rows
            const float* hp = hs + ((size_t)(b * NV + vc) * NL + l) * ND;
            bf8u af[2];
            #pragma unroll
            for (int ks = 0; ks < 2; ++ks) {
                float4 x0 = *(const float4*)&hp[ks * 32 + lq * 8];
                float4 x1 = *(const float4*)&hp[ks * 32 + lq * 8 + 4];
                af[ks].u[0] = pack_bf16(x0.x, x0.y);
                af[ks].u[1] = pack_bf16(x0.z, x0.w);
                af[ks].u[2] = pack_bf16(x1.x, x1.y);
                af[ks].u[3] = pack_bf16(x1.z, x1.w);
            }
            if (Mt == 0) {
                acc00 = __builtin_amdgcn_mfma_f32_16x16x32_bf16(af[0].v, w1f[0][0], acc00, 0, 0, 0);
                acc00 = __builtin_amdgcn_mfma_f32_16x16x32_bf16(af[1].v, w1f[0][1], acc00, 0, 0, 0);
                acc01 = __builtin_amdgcn_mfma_f32_16x16x32_bf16(af[0].v, w1f[1][0], acc01, 0, 0, 0);
                acc01 = __builtin_amdgcn_mfma_f32_16x16x32_bf16(af[1].v, w1f[1][1], acc01, 0, 0, 0);
            } else {
                acc10 = __builtin_amdgcn_mfma_f32_16x16x32_bf16(af[0].v, w1f[0][0], acc10, 0, 0, 0);
                acc10 = __builtin_amdgcn_mfma_f32_16x16x32_bf16(af[1].v, w1f[0][1], acc10, 0, 0, 0);
                acc11 = __builtin_amdgcn_mfma_f32_16x16x32_bf16(af[0].v, w1f[1][0], acc11, 0, 0, 0);
                acc11 = __builtin_amdgcn_mfma_f32_16x16x32_bf16(af[1].v, w1f[1][1], acc11, 0, 0, 0);
            }
        }
        // write A: row v = Mt*16 + lq*4 + r, col c = wave*32 + {lm, 16+lm}
        #pragma unroll
        for (int r = 0; r < 4; ++r) {
            int v0 = lq * 4 + r;
            A_s[v0 * ASTRIDE + wave * 32 + lm]      = f2bf(acc00[r]);
            A_s[v0 * ASTRIDE + wave * 32 + 16 + lm] = f2bf(acc01[r]);
            int v1 = 16 + lq * 4 + r;
            if (v1 < NV) {
                A_s[v1 * ASTRIDE + wave * 32 + lm]      = f2bf(acc10[r]);
                A_s[v1 * ASTRIDE + wave * 32 + 16 + lm] = f2bf(acc11[r]);
            }
        }
    }
    __syncthreads();

    // ---------- phase 3: edge tiles of 16, one wave per tile ----------
    for (int t = wave; t < NT; t += 4) {
        const int ebase = t * 16;
        const int e  = ebase + lm;        // this lane's edge (layer-1 role)
        const int so = srco_s[e];
        const int to = tgto_s[e];
        const float ew = ew_s[e];

        // layer 1: pairwise unpack + pk-friendly math + cvt_pk repack
        bf8u a1[2];
        #pragma unroll
        for (int ks = 0; ks < 2; ++ks) {
            bf8u as, at;
            as.q = *(const uint4*)&A_s[so + ks * 32 + lq * 8];
            at.q = *(const uint4*)&A_s[to + ks * 32 + lq * 8];
            #pragma unroll
            for (int p = 0; p < 4; ++p) {
                int ci = ks * 8 + 2 * p;
                float x0 = bflo(as.u[p]) + bflo(at.u[p])
                         + fmaf(ew, w1l_r[ci],     b1_r[ci]);
                float x1 = bfhi(as.u[p]) + bfhi(at.u[p])
                         + fmaf(ew, w1l_r[ci + 1], b1_r[ci + 1]);
                a1[ks].u[p] = pack_bf16(silu(x0), silu(x1));
            }
        }

        // layer 2: (16 edges x 64) @ (64 x 32) via 4 MFMAs
        f32x4 c0 = {0,0,0,0}, c1 = {0,0,0,0};
        c0 = __builtin_amdgcn_mfma_f32_16x16x32_bf16(a1[0].v, w2f[0][0], c0, 0, 0, 0);
        c0 = __builtin_amdgcn_mfma_f32_16x16x32_bf16(a1[1].v, w2f[0][1], c0, 0, 0, 0);
        c1 = __builtin_amdgcn_mfma_f32_16x16x32_bf16(a1[0].v, w2f[1][0], c1, 0, 0, 0);
        c1 = __builtin_amdgcn_mfma_f32_16x16x32_bf16(a1[1].v, w2f[1][1], c1, 0, 0, 0);

        // epilogue: silu, layer-3 partials (cols lm and 16+lm), rows = edges
        float p0 = silu(c0[0] + b2r0) * w3a + silu(c1[0] + b2r1) * w3b;
        float p1 = silu(c0[1] + b2r0) * w3a + silu(c1[1] + b2r1) * w3b;
        float p2 = silu(c0[2] + b2r0) * w3a + silu(c1[2] + b2r1) * w3b;
        float p3 = silu(c0[3] + b2r0) * w3a + silu(c1[3] + b2r1) * w3b;

        // reduce over 16 cols (butterfly within 16-lane groups)
        #pragma unroll
        for (int s = 1; s < 16; s <<= 1) {
            p0 += __shfl_xor(p0, s);
            p1 += __shfl_xor(p1, s);
            p2 += __shfl_xor(p2, s);
            p3 += __shfl_xor(p3, s);
        }
        // lanes lm<4 store edges: row = lq*4 + (lane&3)
        if (lm < 4) {
            int er = ebase + lq * 4 + (lane & 3);
            if (er < NE) {
                float ps = (lane & 2) ? ((lane & 1) ? p3 : p2)
                                      : ((lane & 1) ? p1 : p0);
                float wgt = sigm(ps + b3v);
                float ewr = ew_s[er];
                out[(size_t)(b * NE + er) * NL + l] = skip * ewr + (1.f - skip) * wgt;
            }
        }
    }
}

extern "C" void kernel_launch(void* const* d_in, const int* in_sizes, int n_in,
                              void* d_out, int out_size, void* d_ws, size_t ws_size,
                              hipStream_t stream) {
    const float* hs   = (const float*)d_in[0];
    const float* ew   = (const float*)d_in[1];
    const float* W1   = (const float*)d_in[2];
    const float* b1   = (const float*)d_in[3];
    const float* W2   = (const float*)d_in[4];
    const float* b2   = (const float*)d_in[5];
    const float* W3   = (const float*)d_in[6];
    const float* b3   = (const float*)d_in[7];
    const float* skip = (const float*)d_in[8];
    const int*   eidx = (const int*)d_in[9];
    float* outp = (float*)d_out;

    dim3 grid(NB * NL);   // 4096 blocks, one per (b, l)
    dim3 block(256);
    hipLaunchKernelGGL(edge_learner_kernel, grid, block, 0, stream,
                       hs, ew, W1, b1, W2, b2, W3, b3, skip, eidx, outp);
}